// Round 1
// baseline (53.440 us; speedup 1.0000x reference)
//
#include <hip/hip_runtime.h>

#define HW 196
#define C  384
#define TK 98
#define NT 512
#define NWAVE (NT/64)

__global__ __launch_bounds__(NT) void sampling_kernel(
    const float* __restrict__ token,
    const float* __restrict__ feature,
    float* __restrict__ out)
{
    __shared__ float tokLds[C];
    __shared__ float score[HW];
    __shared__ float selW[TK];
    __shared__ int   selIdx[TK];
    __shared__ float wsum[NWAVE];
    __shared__ float s_max, s_winv;

    const int tid  = threadIdx.x;
    const int wave = tid >> 6;
    const int lane = tid & 63;
    const int pair = blockIdx.x;

    const float* tokp  = token   + (size_t)pair * C;
    const float* featp = feature + (size_t)pair * (HW * C);

    // stage token row (384 f32) in LDS
    for (int i = tid; i < C; i += NT) tokLds[i] = tokp[i];
    __syncthreads();

    // hoist per-lane token fragment to registers (reused for all 196 rows)
    const float4* t4 = (const float4*)tokLds;
    float4 tb  = t4[lane];
    float4 tb2 = make_float4(0.f, 0.f, 0.f, 0.f);
    if (lane < 32) tb2 = t4[64 + lane];

    const float scale = 0.05103103630798288f;  // 384^-0.5

    // pass 1: scores. Each wave owns rows wave, wave+8, ... (float4 = 16B/lane loads)
    for (int r = wave; r < HW; r += NWAVE) {
        const float4* f4 = (const float4*)(featp + r * C);
        float4 a = f4[lane];
        float p = a.x*tb.x + a.y*tb.y + a.z*tb.z + a.w*tb.w;
        if (lane < 32) {
            float4 a2 = f4[64 + lane];
            p += a2.x*tb2.x + a2.y*tb2.y + a2.z*tb2.z + a2.w*tb2.w;
        }
        #pragma unroll
        for (int off = 32; off > 0; off >>= 1)
            p += __shfl_xor(p, off, 64);
        if (lane == 0) score[r] = p * scale;
    }
    __syncthreads();

    // max over 196 scores (wave 0)
    if (wave == 0) {
        float m = -3.4e38f;
        for (int i = lane; i < HW; i += 64) m = fmaxf(m, score[i]);
        #pragma unroll
        for (int off = 32; off > 0; off >>= 1)
            m = fmaxf(m, __shfl_xor(m, off, 64));
        if (lane == 0) s_max = m;
    }
    __syncthreads();

    // rank-by-counting (exactly jax.lax.top_k's stable tie-break), then
    // compact selected elements by rank. Softmax denom cancels under the
    // renormalization, so weight = exp(s - max) suffices.
    float w = 0.f;
    if (tid < HW) {
        const float si = score[tid];
        int rank = 0;
        for (int j = 0; j < HW; ++j) {
            const float sj = score[j];                 // LDS broadcast
            rank += (int)((sj > si) | ((sj == si) & (j < tid)));
        }
        if (rank < TK) {
            w = __expf(si - s_max);
            selIdx[rank] = tid;
            selW[rank]  = w;
        }
    }
    // block-reduce sum of selected weights
    #pragma unroll
    for (int off = 32; off > 0; off >>= 1) w += __shfl_xor(w, off, 64);
    if (lane == 0) wsum[wave] = w;
    __syncthreads();
    if (tid == 0) {
        float s = 0.f;
        #pragma unroll
        for (int i = 0; i < NWAVE; ++i) s += wsum[i];
        s_winv = 1.f / s;
    }
    __syncthreads();

    // pass 2: out[c] = sum_i w_i * feat[sel_i, c] / W. Rows just read in
    // pass 1 -> L2 hits. threads 0..383 own one channel each (coalesced).
    if (tid < C) {
        float acc = 0.f;
        for (int i = 0; i < TK; ++i)
            acc += selW[i] * featp[(size_t)selIdx[i] * C + tid];
        out[(size_t)pair * C + tid] = acc * s_winv;
    }
}

extern "C" void kernel_launch(void* const* d_in, const int* in_sizes, int n_in,
                              void* d_out, int out_size, void* d_ws, size_t ws_size,
                              hipStream_t stream) {
    const float* token   = (const float*)d_in[0];
    const float* feature = (const float*)d_in[1];
    float* out = (float*)d_out;
    const int pairs = in_sizes[0] / C;   // 8*16*4 = 512
    sampling_kernel<<<pairs, NT, 0, stream>>>(token, feature, out);
}

// Round 2
// 41.013 us; speedup vs baseline: 1.3030x; 1.3030x over previous
//
#include <hip/hip_runtime.h>

#define HW 196
#define C  384
#define TK 98
#define NT 512
#define NWAVE (NT/64)
#define NQUAD ((HW+3)/4)   // 49, and 49*4 == 196 exactly (no tail)

__global__ __launch_bounds__(NT) void sampling_kernel(
    const float* __restrict__ token,
    const float* __restrict__ feature,
    float* __restrict__ out)
{
    __shared__ float tokLds[C];
    __shared__ float score[HW];
    __shared__ float selW[TK];
    __shared__ int   selIdx[TK];
    __shared__ float wsum[NWAVE];
    __shared__ float part[NWAVE][C];   // 12 KB: per-wave pass-2 partials
    __shared__ float s_max, s_winv;

    const int tid  = threadIdx.x;
    const int wave = tid >> 6;
    const int lane = tid & 63;
    const int pair = blockIdx.x;

    const float* tokp  = token   + (size_t)pair * C;
    const float* featp = feature + (size_t)pair * (HW * C);

    // stage token row (384 f32) in LDS
    for (int i = tid; i < C; i += NT) tokLds[i] = tokp[i];
    __syncthreads();

    // per-lane token fragment in registers (reused for all 196 rows)
    const float4* t4 = (const float4*)tokLds;
    float4 tb  = t4[lane];
    float4 tb2 = make_float4(0.f, 0.f, 0.f, 0.f);
    if (lane < 32) tb2 = t4[64 + lane];

    const float scale = 0.05103103630798288f;  // 384^-0.5

    // ---- pass 1: scores, 4 rows per wave-iteration for MLP ----
    // Each lane issues 6 independent float4 loads (96 B) before reducing.
    for (int q = wave; q < NQUAD; q += NWAVE) {
        const int rbase = q * 4;
        float4 a[4], b[4];
        #pragma unroll
        for (int j = 0; j < 4; ++j) {
            const float4* f4 = (const float4*)(featp + (rbase + j) * C);
            a[j] = f4[lane];
            if (lane < 32) b[j] = f4[64 + lane];
        }
        #pragma unroll
        for (int j = 0; j < 4; ++j) {
            float p = a[j].x*tb.x + a[j].y*tb.y + a[j].z*tb.z + a[j].w*tb.w;
            if (lane < 32)
                p += b[j].x*tb2.x + b[j].y*tb2.y + b[j].z*tb2.z + b[j].w*tb2.w;
            #pragma unroll
            for (int off = 32; off > 0; off >>= 1)
                p += __shfl_xor(p, off, 64);
            if (lane == 0) score[rbase + j] = p * scale;
        }
    }
    __syncthreads();

    // ---- max over 196 scores (wave 0) ----
    if (wave == 0) {
        float m = -3.4e38f;
        for (int i = lane; i < HW; i += 64) m = fmaxf(m, score[i]);
        #pragma unroll
        for (int off = 32; off > 0; off >>= 1)
            m = fmaxf(m, __shfl_xor(m, off, 64));
        if (lane == 0) s_max = m;
    }
    __syncthreads();

    // ---- rank-by-counting (jax.lax.top_k stable tie-break) + compact ----
    // Softmax denom cancels under renormalization: weight = exp(s - max).
    float w = 0.f;
    if (tid < HW) {
        const float si = score[tid];
        int rank = 0;
        for (int j = 0; j < HW; ++j) {
            const float sj = score[j];                 // LDS broadcast
            rank += (int)((sj > si) | ((sj == si) & (j < tid)));
        }
        if (rank < TK) {
            w = __expf(si - s_max);
            selIdx[rank] = tid;
            selW[rank]  = w;
        }
    }
    #pragma unroll
    for (int off = 32; off > 0; off >>= 1) w += __shfl_xor(w, off, 64);
    if (lane == 0) wsum[wave] = w;
    __syncthreads();
    if (tid == 0) {
        float s = 0.f;
        #pragma unroll
        for (int i = 0; i < NWAVE; ++i) s += wsum[i];
        s_winv = 1.f / s;
    }
    __syncthreads();

    // ---- pass 2: each wave owns selected rows i = wave, wave+8, ... ----
    // ~12 rows/wave x 1.5 float4/lane, all loads independent -> deep MLP.
    float4 acc_a = make_float4(0.f, 0.f, 0.f, 0.f);
    float4 acc_b = make_float4(0.f, 0.f, 0.f, 0.f);
    for (int i = wave; i < TK; i += NWAVE) {
        const int   r   = selIdx[i];
        const float wgt = selW[i];
        const float4* f4 = (const float4*)(featp + (size_t)r * C);
        float4 a = f4[lane];
        acc_a.x += wgt * a.x; acc_a.y += wgt * a.y;
        acc_a.z += wgt * a.z; acc_a.w += wgt * a.w;
        if (lane < 32) {
            float4 b = f4[64 + lane];
            acc_b.x += wgt * b.x; acc_b.y += wgt * b.y;
            acc_b.z += wgt * b.z; acc_b.w += wgt * b.w;
        }
    }
    float4* pw = (float4*)&part[wave][0];
    pw[lane] = acc_a;
    if (lane < 32) pw[64 + lane] = acc_b;
    __syncthreads();

    // ---- 8-way cross-wave reduction, coalesced store ----
    if (tid < C) {
        float s = 0.f;
        #pragma unroll
        for (int wv = 0; wv < NWAVE; ++wv) s += part[wv][tid];
        out[(size_t)pair * C + tid] = s * s_winv;
    }
}

extern "C" void kernel_launch(void* const* d_in, const int* in_sizes, int n_in,
                              void* d_out, int out_size, void* d_ws, size_t ws_size,
                              hipStream_t stream) {
    const float* token   = (const float*)d_in[0];
    const float* feature = (const float*)d_in[1];
    float* out = (float*)d_out;
    const int pairs = in_sizes[0] / C;   // 8*16*4 = 512
    sampling_kernel<<<pairs, NT, 0, stream>>>(token, feature, out);
}